// Round 2
// baseline (629.234 us; speedup 1.0000x reference)
//
#include <hip/hip_runtime.h>
#include <hip/hip_bf16.h>

typedef _Float16 h2_t  __attribute__((ext_vector_type(2)));
typedef _Float16 f16x8 __attribute__((ext_vector_type(8)));
typedef float    f32x4 __attribute__((ext_vector_type(4)));

#define NLG    196608
#define DIM    256
#define NRELS  237
#define BG     128
#define NN     256
#define MM     (BG*NN)      // 32768
#define G3     768          // 3*DIM
#define NSPLIT 128

// ---- packed f16 dot2 (2 MAC per instr, f32 accumulate) ----
__device__ __forceinline__ float fd2(unsigned int w, unsigned int h, float acc){
  h2_t a = __builtin_bit_cast(h2_t, w);
  h2_t b = __builtin_bit_cast(h2_t, h);
#if __has_builtin(__builtin_amdgcn_fdot2)
  return __builtin_amdgcn_fdot2(a, b, acc, false);
#else
  return acc + (float)a[0]*(float)b[0] + (float)a[1]*(float)b[1];
#endif
}

// ---------------- A0: needed-relation flags from rel_labels ----------------
__global__ void k_needed(const int* __restrict__ rel, int* __restrict__ needed){
  int t = threadIdx.x;
  needed[t] = 0;                 // 256 slots, NRELS=237 used
  __syncthreads();
  if (t < BG) atomicOr(&needed[rel[t]], 1);
}

// ---------------- A1: skip-filtered partial segment sums ----------------
// grid = NSPLIT*4 (split x dim-chunk), block = 256
__global__ __launch_bounds__(256) void k_segsum(const float* __restrict__ lgf,
    const int* __restrict__ lgt, const int* __restrict__ needed,
    float* __restrict__ part, int* __restrict__ cntp){
  int split = blockIdx.x >> 2, chunk = blockIdx.x & 3;
  int c0 = chunk * 64;
  __shared__ float acc[NRELS*64];
  __shared__ int   cacc[NRELS];
  __shared__ int   sneed[NRELS];
  int t = threadIdx.x, lane = t & 63, wv = t >> 6;
  for (int i = t; i < NRELS*64; i += 256) acc[i] = 0.f;
  for (int i = t; i < NRELS; i += 256){ cacc[i] = 0; sneed[i] = needed[i]; }
  __syncthreads();
  const int RPS = NLG / NSPLIT;          // 1536 rows per split
  int rbase = split * RPS;
  for (int it = 0; it < RPS/8; ++it){    // 8 rows/iter (2 per wave)
    int r0 = rbase + it*8 + wv*2;
    int ty0 = lgt[r0], ty1 = lgt[r0+1];
    int nd0 = sneed[ty0], nd1 = sneed[ty1];
    float v0 = 0.f, v1 = 0.f;
    if (nd0) v0 = lgf[(size_t)r0*DIM + c0 + lane];
    if (nd1) v1 = lgf[(size_t)(r0+1)*DIM + c0 + lane];
    if (nd0){ atomicAdd(&acc[ty0*64 + lane], v0);
              if (chunk==0 && lane==0) atomicAdd(&cacc[ty0], 1); }
    if (nd1){ atomicAdd(&acc[ty1*64 + lane], v1);
              if (chunk==0 && lane==0) atomicAdd(&cacc[ty1], 1); }
  }
  __syncthreads();
  for (int i = t; i < NRELS*64; i += 256){
    int r = i >> 6, d = i & 63;
    part[((size_t)split*NRELS + r)*DIM + c0 + d] = acc[i];
  }
  if (chunk==0) for (int i = t; i < NRELS; i += 256) cntp[split*NRELS + i] = cacc[i];
}

// ---------------- A2: reduce partials -> means ----------------
__global__ __launch_bounds__(256) void k_means(const float* __restrict__ part,
      const int* __restrict__ cntp, float* __restrict__ means){
  int r = blockIdx.x, d = threadIdx.x;
  float s = 0.f;
  for (int sp = 0; sp < NSPLIT; ++sp) s += part[((size_t)sp*NRELS + r)*DIM + d];
  int c = 0;
  for (int sp = 0; sp < NSPLIT; ++sp) c += cntp[sp*NRELS + r];
  means[r*DIM + d] = (c > 0) ? (s / (float)c) : 0.f;
}

// ---------------- B0: X16 = f16(relu(emds+bias)), h0 = max_n(node) ----------------
__global__ __launch_bounds__(256) void k_prep(const float* __restrict__ emds,
     const float* __restrict__ gbias, _Float16* __restrict__ X16, float* __restrict__ h0){
  int b = blockIdx.x, d = threadIdx.x;
  float bi = gbias[d];
  float mx = -3.4e38f;
  const float* src = emds + (size_t)b*NN*DIM + d;
  _Float16* dst = X16 + (size_t)b*NN*DIM + d;
  #pragma unroll 4
  for (int n = 0; n < NN; ++n){
    float v = src[(size_t)n*DIM];
    mx = fmaxf(mx, v);
    dst[(size_t)n*DIM] = (_Float16)fmaxf(v + bi, 0.f);
  }
  h0[b*DIM + d] = mx;
}

// ---------------- B2: weight conversions to f16 ----------------
// wswz layout: uint4 index [c*768 + j] holds w_hh_b[j][8c..8c+7] as 4x h2
// wih16 layout: row-major f16 [768][256]
__global__ __launch_bounds__(256) void k_wconv(const float* __restrict__ whh,
      const float* __restrict__ wih, uint4* __restrict__ wswz, f16x8* __restrict__ wih16){
  int tid = blockIdx.x*256 + threadIdx.x;   // 0..24575
  int c = tid / G3, j = tid - c*G3;
  const float* s1 = whh + (size_t)j*DIM + c*8;
  uint4 o; h2_t p;
  p[0]=(_Float16)s1[0]; p[1]=(_Float16)s1[1]; o.x=__builtin_bit_cast(unsigned int,p);
  p[0]=(_Float16)s1[2]; p[1]=(_Float16)s1[3]; o.y=__builtin_bit_cast(unsigned int,p);
  p[0]=(_Float16)s1[4]; p[1]=(_Float16)s1[5]; o.z=__builtin_bit_cast(unsigned int,p);
  p[0]=(_Float16)s1[6]; p[1]=(_Float16)s1[7]; o.w=__builtin_bit_cast(unsigned int,p);
  wswz[(size_t)c*G3 + j] = o;
  const float* s2 = wih + (size_t)j*DIM + c*8;
  f16x8 v;
  #pragma unroll
  for (int e = 0; e < 8; ++e) v[e] = (_Float16)s2[e];
  wih16[(size_t)j*32 + c] = v;
}

// ---------------- C: gi = X @ w_ih_b^T + b_ih_b  (f16 MFMA, f32 out) ----------------
// grid = (MM/64)*(G3/64) = 512*12, block = 256 (4 waves, 32x32 quadrant each)
__global__ __launch_bounds__(256) void k_gemm_gi(const _Float16* __restrict__ X16,
        const _Float16* __restrict__ wih16, const float* __restrict__ bih,
        float* __restrict__ gi){
  __shared__ __align__(16) _Float16 Xs[64*136];   // K staged in halves of 128, +8 pad
  __shared__ __align__(16) _Float16 Ws[64*136];
  int m0 = (blockIdx.x / 12) * 64;
  int n0 = (blockIdx.x % 12) * 64;
  int t = threadIdx.x;
  int w = t >> 6, l = t & 63;
  int wm = (w & 1) * 32, wn = (w >> 1) * 32;
  int fr = l & 15, kg = l >> 4;     // fragment row, k-group
  f32x4 acc[2][2] = {};
  for (int kh = 0; kh < 2; ++kh){
    if (kh) __syncthreads();
    for (int rnd = 0; rnd < 4; ++rnd){
      int chunk = rnd*256 + t;        // 64 rows x 16 chunks of 8 f16
      int r = chunk >> 4, cc = chunk & 15;
      *(f16x8*)&Xs[r*136 + cc*8] = *(const f16x8*)&X16[(size_t)(m0+r)*DIM + kh*128 + cc*8];
      *(f16x8*)&Ws[r*136 + cc*8] = *(const f16x8*)&wih16[(size_t)(n0+r)*DIM + kh*128 + cc*8];
    }
    __syncthreads();
    #pragma unroll
    for (int kk = 0; kk < 4; ++kk){
      int kcol = kk*32 + kg*8;
      f16x8 a0 = *(const f16x8*)&Xs[(wm + fr)*136 + kcol];
      f16x8 a1 = *(const f16x8*)&Xs[(wm + 16 + fr)*136 + kcol];
      f16x8 b0 = *(const f16x8*)&Ws[(wn + fr)*136 + kcol];
      f16x8 b1 = *(const f16x8*)&Ws[(wn + 16 + fr)*136 + kcol];
      acc[0][0] = __builtin_amdgcn_mfma_f32_16x16x32_f16(a0,b0,acc[0][0],0,0,0);
      acc[0][1] = __builtin_amdgcn_mfma_f32_16x16x32_f16(a0,b1,acc[0][1],0,0,0);
      acc[1][0] = __builtin_amdgcn_mfma_f32_16x16x32_f16(a1,b0,acc[1][0],0,0,0);
      acc[1][1] = __builtin_amdgcn_mfma_f32_16x16x32_f16(a1,b1,acc[1][1],0,0,0);
    }
  }
  // C/D layout: col = lane&15 (N), row = (lane>>4)*4 + v (M)
  #pragma unroll
  for (int i = 0; i < 2; ++i)
  #pragma unroll
  for (int j = 0; j < 2; ++j){
    int col = n0 + wn + j*16 + fr;
    float bv = bih[col];
    #pragma unroll
    for (int v = 0; v < 4; ++v){
      int row = m0 + wm + i*16 + kg*4 + v;
      gi[(size_t)row*G3 + col] = acc[i][j][v] + bv;
    }
  }
}

// ---------------- D: GRU. blocks 0..127 backward chains (256 steps),
//                       blocks 128..255 forward 2 steps. block = 768 ----------------
__global__ __launch_bounds__(768) void k_gru(const uint4* __restrict__ wswz,
      const float* __restrict__ gi, const float* __restrict__ h0,
      const float* __restrict__ bhh,
      const float* __restrict__ emds, const float* __restrict__ gbias,
      const float* __restrict__ wihf, const float* __restrict__ whhf,
      const float* __restrict__ bihf, const float* __restrict__ bhhf,
      float* __restrict__ fwd0, float* __restrict__ fwd1,
      float* __restrict__ bwd1, float* __restrict__ bwd0){
  int j = threadIdx.x;
  if (blockIdx.x < 128){
    // ---- backward chain for graph b: weights (row j) resident in 128 VGPRs as f16 ----
    int b = blockIdx.x;
    __shared__ __align__(16) _Float16 hbuf[2][256];
    __shared__ float rz[512];
    __shared__ float hn_[256];
    __shared__ float in_[256];
    uint4 w4[32];
    #pragma unroll
    for (int c = 0; c < 32; ++c) w4[c] = wswz[c*G3 + j];
    float bh = bhh[j];
    float hold = 0.f;
    if (j < 256){
      hold = h0[b*DIM + j];
      hbuf[0][j] = (_Float16)hold;
    }
    const float* gibase = gi + (size_t)b*NN*G3;
    float gcur = gibase[(size_t)255*G3 + j];   // t_rev = 255 first
    __syncthreads();
    int cur = 0;
    for (int s = 0; s < 256; ++s){
      float gnext = (s < 255) ? gibase[(size_t)(254 - s)*G3 + j] : 0.f;
      const uint4* hb = (const uint4*)&hbuf[cur][0];
      float a0=0.f, a1=0.f, a2=0.f, a3=0.f;
      #pragma unroll
      for (int c = 0; c < 32; ++c){
        uint4 hv = hb[c];
        a0 = fd2(w4[c].x, hv.x, a0);
        a1 = fd2(w4[c].y, hv.y, a1);
        a2 = fd2(w4[c].z, hv.z, a2);
        a3 = fd2(w4[c].w, hv.w, a3);
      }
      float gh = (a0+a1)+(a2+a3) + bh;
      if (j < 512) rz[j] = gh + gcur;
      else { hn_[j-512] = gh; in_[j-512] = gcur; }
      __syncthreads();
      if (j < 256){
        float r = 1.f/(1.f + __expf(-rz[j]));
        float z = 1.f/(1.f + __expf(-rz[256+j]));
        float n = tanhf(in_[j] + r*hn_[j]);
        float hnew = (1.f - z)*n + z*hold;
        hold = hnew;
        hbuf[cur^1][j] = (_Float16)hnew;
        if (s == 254) bwd1[b*DIM + j] = hnew;   // state after 255 steps
        if (s == 255) bwd0[b*DIM + j] = hnew;   // final state
      }
      __syncthreads();
      cur ^= 1;
      gcur = gnext;
    }
  } else {
    // ---- forward: only fwd[0], fwd[1] needed (2 steps), f32 throughout ----
    int b = blockIdx.x - 128;
    __shared__ float xv[2][256];
    __shared__ float hcur[256];
    __shared__ float frz[512];
    __shared__ float fhn[256], fin[256];
    if (j < 256){
      float bi = gbias[j];
      xv[0][j] = fmaxf(emds[(size_t)b*NN*DIM + 0*DIM + j] + bi, 0.f);
      xv[1][j] = fmaxf(emds[(size_t)b*NN*DIM + 1*DIM + j] + bi, 0.f);
      hcur[j] = h0[b*DIM + j];
    }
    __syncthreads();
    for (int st = 0; st < 2; ++st){
      const float4* wi = (const float4*)(wihf + (size_t)j*DIM);
      const float4* wh = (const float4*)(whhf + (size_t)j*DIM);
      float gi_ = bihf[j], gh_ = bhhf[j];
      #pragma unroll 8
      for (int c = 0; c < 64; ++c){
        float4 a = wi[c];
        gi_ += a.x*xv[st][c*4] + a.y*xv[st][c*4+1] + a.z*xv[st][c*4+2] + a.w*xv[st][c*4+3];
        float4 h4 = wh[c];
        gh_ += h4.x*hcur[c*4] + h4.y*hcur[c*4+1] + h4.z*hcur[c*4+2] + h4.w*hcur[c*4+3];
      }
      if (j < 512) frz[j] = gi_ + gh_;
      else { fhn[j-512] = gh_; fin[j-512] = gi_; }
      __syncthreads();
      if (j < 256){
        float r = 1.f/(1.f + __expf(-frz[j]));
        float z = 1.f/(1.f + __expf(-frz[256+j]));
        float n = tanhf(fin[j] + r*fhn[j]);
        float hnew = (1.f - z)*n + z*hcur[j];
        hcur[j] = hnew;
        if (st == 0) fwd0[b*DIM + j] = hnew; else fwd1[b*DIM + j] = hnew;
      }
      __syncthreads();
    }
  }
}

// ---------------- E: head — W3/relu, features, W1, W2 (f32) ----------------
__global__ __launch_bounds__(256) void k_head(const float* __restrict__ fwd0,
     const float* __restrict__ fwd1, const float* __restrict__ bwd1,
     const float* __restrict__ bwd0, const float* __restrict__ means,
     const int* __restrict__ rel,
     const float* __restrict__ W3, const float* __restrict__ b3,
     const float* __restrict__ W1, const float* __restrict__ b1,
     const float* __restrict__ W2, const float* __restrict__ b2,
     float* __restrict__ out){
  int b = blockIdx.x, d = threadIdx.x;
  __shared__ float cat0[512], cat1[512], feat[256];
  cat0[d] = fwd0[b*DIM+d]; cat0[256+d] = bwd0[b*DIM+d];
  cat1[d] = fwd1[b*DIM+d]; cat1[256+d] = bwd1[b*DIM+d];
  __syncthreads();
  const float4* w3r = (const float4*)(W3 + (size_t)d*512);
  float hd = b3[d], td = b3[d];
  #pragma unroll 8
  for (int c = 0; c < 128; ++c){
    float4 w = w3r[c];
    hd += w.x*cat0[c*4] + w.y*cat0[c*4+1] + w.z*cat0[c*4+2] + w.w*cat0[c*4+3];
    td += w.x*cat1[c*4] + w.y*cat1[c*4+1] + w.z*cat1[c*4+2] + w.w*cat1[c*4+3];
  }
  int lab = rel[b];
  feat[d] = fmaxf(hd, 0.f) + means[(size_t)lab*DIM + d] - fmaxf(td, 0.f);
  __syncthreads();
  const float4* w1r = (const float4*)(W1 + (size_t)d*DIM);
  float s = b1[d];
  #pragma unroll 8
  for (int c = 0; c < 64; ++c){
    float4 w = w1r[c];
    s += w.x*feat[c*4] + w.y*feat[c*4+1] + w.z*feat[c*4+2] + w.w*feat[c*4+3];
  }
  float v = W2[d] * s;
  #pragma unroll
  for (int o = 32; o > 0; o >>= 1) v += __shfl_down(v, o, 64);
  __shared__ float red[4];
  if ((d & 63) == 0) red[d >> 6] = v;
  __syncthreads();
  if (d == 0) out[b] = red[0] + red[1] + red[2] + red[3] + b2[0];
}

extern "C" void kernel_launch(void* const* d_in, const int* in_sizes, int n_in,
                              void* d_out, int out_size, void* d_ws, size_t ws_size,
                              hipStream_t stream){
  const float* lg_feats = (const float*)d_in[0];
  const int*   lg_type  = (const int*)d_in[1];
  const float* emds     = (const float*)d_in[2];
  const int*   rel      = (const int*)d_in[3];
  const float* gbias    = (const float*)d_in[4];
  const float* wihf     = (const float*)d_in[5];
  const float* whhf     = (const float*)d_in[6];
  const float* bihf     = (const float*)d_in[7];
  const float* bhhf     = (const float*)d_in[8];
  const float* wihb     = (const float*)d_in[9];
  const float* whhb     = (const float*)d_in[10];
  const float* bihb     = (const float*)d_in[11];
  const float* bhhb     = (const float*)d_in[12];
  const float* W3 = (const float*)d_in[13];
  const float* b3 = (const float*)d_in[14];
  const float* W1 = (const float*)d_in[15];
  const float* b1 = (const float*)d_in[16];
  const float* W2 = (const float*)d_in[17];
  const float* b2 = (const float*)d_in[18];
  float* out = (float*)d_out;

  char* ws = (char*)d_ws;
  size_t off = 0;
  auto alloc = [&](size_t bytes){ size_t o = off; off += (bytes + 255) & ~(size_t)255; return o; };
  size_t o_needed = alloc(256*4);
  size_t o_cntp   = alloc((size_t)NSPLIT*NRELS*4);
  size_t o_means  = alloc((size_t)NRELS*DIM*4);
  size_t o_h0     = alloc((size_t)BG*DIM*4);
  size_t o_X16    = alloc((size_t)MM*DIM*2);
  size_t o_wswz   = alloc((size_t)G3*DIM*2);
  size_t o_wih16  = alloc((size_t)G3*DIM*2);
  size_t o_f0     = alloc((size_t)BG*DIM*4);
  size_t o_f1     = alloc((size_t)BG*DIM*4);
  size_t o_b1v    = alloc((size_t)BG*DIM*4);
  size_t o_b0v    = alloc((size_t)BG*DIM*4);
  // big region: partial sums first (31 MB), then reused for gi (100.7 MB)
  size_t o_big    = alloc((size_t)MM*G3*4);
  (void)o_big; (void)ws_size; (void)in_sizes; (void)n_in; (void)out_size;

  int*       needed = (int*)(ws + o_needed);
  int*       cntp   = (int*)(ws + o_cntp);
  float*     means  = (float*)(ws + o_means);
  float*     h0     = (float*)(ws + o_h0);
  _Float16*  X16    = (_Float16*)(ws + o_X16);
  uint4*     wswz   = (uint4*)(ws + o_wswz);
  f16x8*     wih16  = (f16x8*)(ws + o_wih16);
  float*     f0     = (float*)(ws + o_f0);
  float*     f1     = (float*)(ws + o_f1);
  float*     b1v    = (float*)(ws + o_b1v);
  float*     b0v    = (float*)(ws + o_b0v);
  float*     part   = (float*)(ws + o_big);
  float*     gi     = (float*)(ws + o_big);

  k_prep  <<<BG, 256, 0, stream>>>(emds, gbias, X16, h0);
  k_wconv <<<(G3*32)/256, 256, 0, stream>>>(whhb, wihb, wswz, wih16);
  k_needed<<<1, 256, 0, stream>>>(rel, needed);
  k_segsum<<<NSPLIT*4, 256, 0, stream>>>(lg_feats, lg_type, needed, part, cntp);
  k_means <<<NRELS, 256, 0, stream>>>(part, cntp, means);
  k_gemm_gi<<<(MM/64)*(G3/64), 256, 0, stream>>>(X16, (const _Float16*)wih16, bihb, gi);
  k_gru   <<<256, 768, 0, stream>>>(wswz, gi, h0, bhhb, emds, gbias,
                                    wihf, whhf, bihf, bhhf, f0, f1, b1v, b0v);
  k_head  <<<BG, 256, 0, stream>>>(f0, f1, b1v, b0v, means, rel,
                                   W3, b3, W1, b1, W2, b2, out);
}